// Round 9
// baseline (72.390 us; speedup 1.0000x reference)
//
#include <hip/hip_runtime.h>
#include <math.h>

// DCCA loss: H1,H2 (m=2048, n=64, k=128) fp32.
// gram: fp32 k-quarter stages DMA'd via global_load_lds (triple-buffered, counted
//       vmcnt(4), raw s_barrier -- T3/T4), bf16 hi/lo conversion at fragment read,
//       source-swizzled LDS layout (T2 via m173), job-split waves (disjoint quads).
// reduce: 160x1024 tree-reduce of 1024 partial slabs into sig.
// solve: MFMA Newton inverse (3 iters), corr^2 = <X1, S12 X2 S12^T>, -sqrt.
#define TPB 2
#define GRID1 1024             // gram blocks / partial slabs
#define NSTAGE 8               // k-quarter stages per block (TPB tiles x 4 quarters)

// c = (1 - 1/m)^2 / (m*(m-1)) = 2047 / 2048^3
#define CSCALE 2.3830240e-7f
#define RIDGE 1e-4f

typedef __bf16 bf16x8 __attribute__((ext_vector_type(8)));
typedef float f32x16 __attribute__((ext_vector_type(16)));

#define MFMA32(A, B, C) __builtin_amdgcn_mfma_f32_32x32x16_bf16(A, B, C, 0, 0, 0)

#define GLL(gsrc, ldst)                                                        \
    __builtin_amdgcn_global_load_lds(                                          \
        (const __attribute__((address_space(1))) unsigned int*)(gsrc),         \
        (__attribute__((address_space(3))) unsigned int*)(ldst), 16, 0, 0)

#define WAITVM(N) asm volatile("s_waitcnt vmcnt(" #N ")" ::: "memory")
#define MEMFENCE() asm volatile("" ::: "memory")

// global quad id q -> (matrix, row-block, col-block); q0..2 S11, 3..5 S22, 6..9 S12
__device__ __constant__ int kMat[10] = {0,0,0, 1,1,1, 2,2,2,2};
__device__ __constant__ int kQi [10] = {0,1,1, 0,1,1, 0,0,1,1};
__device__ __constant__ int kQj [10] = {0,0,1, 0,0,1, 0,1,0,1};

// 256 threads = 4 job-split waves: w0 -> S11 quads (0,0),(1,0),(1,1); w1 -> S22 same;
// w2 -> S12 rows 0-31 (quads (0,0),(0,1)); w3 -> S12 rows 32-63 ((1,0),(1,1)).
// LDS stage layout (16B granules): slot = v*512 + row*8 + (g ^ (row&7)), g = logical
// 4-float granule of the 32-col quarter. DMA dest is linear; swizzle applied on the
// global SOURCE address (m173) and re-applied on ds_read.
template <bool PARTIALS>
__global__ __launch_bounds__(256, 3) void gram_kernel(const float* __restrict__ H1,
                                                      const float* __restrict__ H2,
                                                      float* __restrict__ sig,
                                                      float* __restrict__ part) {
    __shared__ __attribute__((aligned(16))) float sbuf[3 * 4096];  // 3 x 16 KB
    const int tid = threadIdx.x;
    const int w = tid >> 6;
    const int lane = tid & 63;
    const int l31 = lane & 31;
    const int lhi = lane >> 5;

    f32x16 a0 = {}, a1 = {}, a2 = {};

    auto STAGE = [&](int s) {
        const int tile = blockIdx.x * TPB + (s >> 2);
        const int kq = s & 3;
        const size_t tb = (size_t)tile * 8192 + kq * 32;      // float offset
        float* dbase = sbuf + (s % 3) * 4096 + w * 1024;       // wave-uniform dest
        #pragma unroll
        for (int i = 0; i < 4; ++i) {
            int slot = (w << 8) + (i << 6) + lane;             // 16B-granule index
            int v = slot >> 9, rem = slot & 511;
            int row = rem >> 3, gp = rem & 7;
            int g = gp ^ (row & 7);                            // inverse swizzle on src
            const float* src = (v ? H2 : H1) + tb + (size_t)row * 128 + (g << 2);
            GLL(src, dbase + (i << 8));
        }
    };

    // read 8 floats of (view v, row r, granule pair gb,gb+1), make hi+lo bf16 frags
    auto RD8HL = [&](const float* bufc, int v, int r, int gb, bf16x8& hi, bf16x8& lo) {
        const float* p = bufc + v * 2048 + r * 32;
        const int m = r & 7;
        float4 x = *(const float4*)(p + ((gb ^ m) << 2));
        float4 y = *(const float4*)(p + (((gb + 1) ^ m) << 2));
        float f[8] = {x.x, x.y, x.z, x.w, y.x, y.y, y.z, y.w};
        #pragma unroll
        for (int j = 0; j < 8; ++j) {
            __bf16 h = (__bf16)f[j];
            hi[j] = h;
            lo[j] = (__bf16)(f[j] - (float)h);
        }
    };

    STAGE(0);
    STAGE(1);

    #pragma unroll
    for (int s = 0; s < NSTAGE; ++s) {
        if (s < NSTAGE - 1) WAITVM(4);   // stage s done; s+1 (4 calls) may stay in flight
        else                WAITVM(0);
        __builtin_amdgcn_s_barrier();    // all waves' quarters of stage s visible
        MEMFENCE();                      // no ds_read/GLL crosses the barrier
        if (s + 2 < NSTAGE) STAGE(s + 2);

        const float* bufc = sbuf + (s % 3) * 4096;
        if (w < 2) {
            #pragma unroll
            for (int ktl = 0; ktl < 2; ++ktl) {
                const int gb = ktl * 4 + lhi * 2;
                bf16x8 h0, l0, h1, l1;
                RD8HL(bufc, w, l31, gb, h0, l0);
                RD8HL(bufc, w, 32 + l31, gb, h1, l1);
                a0 = MFMA32(h0, h0, a0); a0 = MFMA32(h0, l0, a0); a0 = MFMA32(l0, h0, a0);
                a1 = MFMA32(h1, h0, a1); a1 = MFMA32(h1, l0, a1); a1 = MFMA32(l1, h0, a1);
                a2 = MFMA32(h1, h1, a2); a2 = MFMA32(h1, l1, a2); a2 = MFMA32(l1, h1, a2);
            }
        } else {
            const int ar = (w - 2) * 32 + l31;
            #pragma unroll
            for (int ktl = 0; ktl < 2; ++ktl) {
                const int gb = ktl * 4 + lhi * 2;
                bf16x8 Ah, Al, B0h, B0l, B1h, B1l;
                RD8HL(bufc, 0, ar, gb, Ah, Al);
                RD8HL(bufc, 1, l31, gb, B0h, B0l);
                RD8HL(bufc, 1, 32 + l31, gb, B1h, B1l);
                a0 = MFMA32(Ah, B0h, a0); a0 = MFMA32(Ah, B0l, a0); a0 = MFMA32(Al, B0h, a0);
                a1 = MFMA32(Ah, B1h, a1); a1 = MFMA32(Ah, B1l, a1); a1 = MFMA32(Al, B1h, a1);
            }
        }
    }

    // Flush: quads are wave-disjoint -> non-atomic partial dump (or atomic fallback).
    const int q0 = (w == 0) ? 0 : (w == 1) ? 3 : (w == 2) ? 6 : 8;
    const int nq = (w < 2) ? 3 : 2;
    f32x16 A[3] = {a0, a1, a2};
    if (PARTIALS) {
        float* dst = part + (size_t)blockIdx.x * 10240 + q0 * 1024;
        #pragma unroll
        for (int qq = 0; qq < 3; ++qq) {
            if (qq < nq) {
                #pragma unroll
                for (int rg = 0; rg < 16; ++rg) {
                    // C/D 32x32 layout: col = lane&31, row = (rg&3)+8*(rg>>2)+4*(lane>>5)
                    int row = (rg & 3) + 8 * (rg >> 2) + 4 * lhi;
                    dst[qq * 1024 + row * 32 + l31] = A[qq][rg];
                }
            }
        }
    } else {
        #pragma unroll
        for (int qq = 0; qq < 3; ++qq) {
            if (qq < nq) {
                const int q = q0 + qq;
                #pragma unroll
                for (int rg = 0; rg < 16; ++rg) {
                    int row = (rg & 3) + 8 * (rg >> 2) + 4 * lhi;
                    atomicAdd(&sig[kMat[q] * 4096 + (kQi[q] * 32 + row) * 64 + kQj[q] * 32 + l31],
                              A[qq][rg]);
                }
            }
        }
    }
}

// 160 blocks x 1024 threads: block owns 64 partial-space slots; wave w of 16 sums
// slabs {w, w+16, ...}; cross-wave combine in LDS; scatter into sig.
__global__ __launch_bounds__(1024) void reduce_kernel(const float* __restrict__ part,
                                                      float* __restrict__ sig) {
    __shared__ float buf[16][64];
    const int tid = threadIdx.x;
    const int w = tid >> 6;
    const int lane = tid & 63;
    const int o0 = blockIdx.x * 64;

    float s = 0.0f;
    for (int p = w; p < GRID1; p += 16)
        s += part[(size_t)p * 10240 + o0 + lane];
    buf[w][lane] = s;
    __syncthreads();

    if (w == 0) {
        float v = 0.0f;
        #pragma unroll
        for (int i = 0; i < 16; ++i) v += buf[i][lane];
        int o = o0 + lane;
        int q = o >> 10, idx = o & 1023;
        int r = idx >> 5, c = idx & 31;
        sig[kMat[q] * 4096 + (kQi[q] * 32 + r) * 64 + kQj[q] * 32 + c] = v;
    }
}

// One block, 512 threads (8 waves). Newton inverse on MFMA:
//   X0 = (64/tr A) I;  X <- 2X - X*A*X  (3 iters; residual (0.033)^8 ~ 1e-12)
//   corr^2 = <X1, S12*X2*S12^T>  transpose-free via mfma(A,B)=A*B^T + symmetry.
#define SST 72
#define SPL (64 * SST)
// plane ids: 0/1 A1 h/l, 2/3 A2 h/l, 4/5 X1 h/l, 6/7 X2 h/l, 8/9 W1|S12 h/l, 10/11 W2|Z h/l

__global__ __launch_bounds__(512, 1) void solve_kernel(const float* __restrict__ sig,
                                                       float* __restrict__ out) {
    __shared__ __attribute__((aligned(16))) __bf16 pl[12 * SPL];
    __shared__ float ainv[2];
    __shared__ float rbuf[4];
    const int tid = threadIdx.x;
    const int w = tid >> 6, lane = tid & 63, l31 = lane & 31, lhi = lane >> 5;
    const int g = w >> 2;          // matrix group: 0 -> S11, 1 -> S22
    const int qw = w & 3, qi = qw >> 1, qj = qw & 1;
    const int ra = qi * 32 + l31;  // A-operand fragment row
    const int rb = qj * 32 + l31;  // B-operand fragment row

    // Load A = CSCALE*Gram + ridge, symmetric reconstruct (sig quad (0,1) is zeros).
    for (int idx = tid; idx < 4096; idx += 512) {
        int r = idx >> 6, c = idx & 63;
        int src = (r < 32 && c >= 32) ? (c * 64 + r) : idx;
        float rg = (r == c) ? RIDGE : 0.0f;
        float v1 = CSCALE * sig[src] + rg;
        float v2 = CSCALE * sig[4096 + src] + rg;
        __bf16 h1 = (__bf16)v1, h2 = (__bf16)v2;
        pl[0 * SPL + r * SST + c] = h1;
        pl[1 * SPL + r * SST + c] = (__bf16)(v1 - (float)h1);
        pl[2 * SPL + r * SST + c] = h2;
        pl[3 * SPL + r * SST + c] = (__bf16)(v2 - (float)h2);
    }
    if (w == 0 || w == 4) {        // alpha_inv = 64 / tr(A)
        int mg = (w == 4);
        float d = CSCALE * sig[mg * 4096 + lane * 65] + RIDGE;
        #pragma unroll
        for (int off = 32; off; off >>= 1) d += __shfl_xor(d, off, 64);
        if (lane == 0) ainv[mg] = 64.0f / d;
    }
    __syncthreads();

    // X0 = ainv * I
    for (int idx = tid; idx < 4096; idx += 512) {
        int r = idx >> 6, c = idx & 63;
        float v1 = (r == c) ? ainv[0] : 0.0f;
        float v2 = (r == c) ? ainv[1] : 0.0f;
        __bf16 h1 = (__bf16)v1, h2 = (__bf16)v2;
        pl[4 * SPL + r * SST + c] = h1;
        pl[5 * SPL + r * SST + c] = (__bf16)(v1 - (float)h1);
        pl[6 * SPL + r * SST + c] = h2;
        pl[7 * SPL + r * SST + c] = (__bf16)(v2 - (float)h2);
    }
    __syncthreads();

    for (int it = 0; it < 3; ++it) {
        // W = X * A
        f32x16 accw = {};
        #pragma unroll
        for (int ks = 0; ks < 4; ++ks) {
            int col = ks * 16 + lhi * 8;
            bf16x8 xh = *(const bf16x8*)&pl[(4 + 2 * g) * SPL + ra * SST + col];
            bf16x8 xl = *(const bf16x8*)&pl[(5 + 2 * g) * SPL + ra * SST + col];
            bf16x8 ah = *(const bf16x8*)&pl[(0 + 2 * g) * SPL + rb * SST + col];
            bf16x8 al = *(const bf16x8*)&pl[(1 + 2 * g) * SPL + rb * SST + col];
            accw = MFMA32(xh, ah, accw);
            accw = MFMA32(xh, al, accw);
            accw = MFMA32(xl, ah, accw);
        }
        #pragma unroll
        for (int rg = 0; rg < 16; ++rg) {
            int row = qi * 32 + (rg & 3) + 8 * (rg >> 2) + 4 * lhi;
            int col = qj * 32 + l31;
            float v = accw[rg];
            __bf16 h = (__bf16)v;
            pl[(8 + 2 * g) * SPL + row * SST + col] = h;
            pl[(9 + 2 * g) * SPL + row * SST + col] = (__bf16)(v - (float)h);
        }
        __syncthreads();

        // S = W * X ; X <- 2X - S
        f32x16 accs = {};
        #pragma unroll
        for (int ks = 0; ks < 4; ++ks) {
            int col = ks * 16 + lhi * 8;
            bf16x8 wh = *(const bf16x8*)&pl[(8 + 2 * g) * SPL + ra * SST + col];
            bf16x8 wl = *(const bf16x8*)&pl[(9 + 2 * g) * SPL + ra * SST + col];
            bf16x8 xh = *(const bf16x8*)&pl[(4 + 2 * g) * SPL + rb * SST + col];
            bf16x8 xl = *(const bf16x8*)&pl[(5 + 2 * g) * SPL + rb * SST + col];
            accs = MFMA32(wh, xh, accs);
            accs = MFMA32(wh, xl, accs);
            accs = MFMA32(wl, xh, accs);
        }
        __syncthreads();   // all X reads done before X writes
        #pragma unroll
        for (int rg = 0; rg < 16; ++rg) {
            int row = qi * 32 + (rg & 3) + 8 * (rg >> 2) + 4 * lhi;
            int col = qj * 32 + l31;
            float xv = (float)pl[(4 + 2 * g) * SPL + row * SST + col]
                     + (float)pl[(5 + 2 * g) * SPL + row * SST + col];
            float nv = 2.0f * xv - accs[rg];
            __bf16 h = (__bf16)nv;
            pl[(4 + 2 * g) * SPL + row * SST + col] = h;
            pl[(5 + 2 * g) * SPL + row * SST + col] = (__bf16)(nv - (float)h);
        }
        __syncthreads();
    }

    // S12 -> planes 8/9
    for (int idx = tid; idx < 4096; idx += 512) {
        int r = idx >> 6, c = idx & 63;
        float v = CSCALE * sig[8192 + idx];
        __bf16 h = (__bf16)v;
        pl[8 * SPL + r * SST + c] = h;
        pl[9 * SPL + r * SST + c] = (__bf16)(v - (float)h);
    }
    __syncthreads();

    // Z = S12 * X2 -> planes 10/11 (group 1)
    if (g == 1) {
        f32x16 accz = {};
        #pragma unroll
        for (int ks = 0; ks < 4; ++ks) {
            int col = ks * 16 + lhi * 8;
            bf16x8 sh = *(const bf16x8*)&pl[8 * SPL + ra * SST + col];
            bf16x8 sl = *(const bf16x8*)&pl[9 * SPL + ra * SST + col];
            bf16x8 xh = *(const bf16x8*)&pl[6 * SPL + rb * SST + col];
            bf16x8 xl = *(const bf16x8*)&pl[7 * SPL + rb * SST + col];
            accz = MFMA32(sh, xh, accz);
            accz = MFMA32(sh, xl, accz);
            accz = MFMA32(sl, xh, accz);
        }
        #pragma unroll
        for (int rg = 0; rg < 16; ++rg) {
            int row = qi * 32 + (rg & 3) + 8 * (rg >> 2) + 4 * lhi;
            int col = qj * 32 + l31;
            float v = accz[rg];
            __bf16 h = (__bf16)v;
            pl[10 * SPL + row * SST + col] = h;
            pl[11 * SPL + row * SST + col] = (__bf16)(v - (float)h);
        }
    }
    __syncthreads();

    // M = Z * S12^T (group 0); corr^2 += M .* X1
    if (g == 0) {
        f32x16 accm = {};
        #pragma unroll
        for (int ks = 0; ks < 4; ++ks) {
            int col = ks * 16 + lhi * 8;
            bf16x8 zh = *(const bf16x8*)&pl[10 * SPL + ra * SST + col];
            bf16x8 zl = *(const bf16x8*)&pl[11 * SPL + ra * SST + col];
            bf16x8 sh = *(const bf16x8*)&pl[8 * SPL + rb * SST + col];
            bf16x8 sl = *(const bf16x8*)&pl[9 * SPL + rb * SST + col];
            accm = MFMA32(zh, sh, accm);
            accm = MFMA32(zh, sl, accm);
            accm = MFMA32(zl, sh, accm);
        }
        float p = 0.0f;
        #pragma unroll
        for (int rg = 0; rg < 16; ++rg) {
            int row = qi * 32 + (rg & 3) + 8 * (rg >> 2) + 4 * lhi;
            int col = qj * 32 + l31;
            float x1v = (float)pl[4 * SPL + row * SST + col]
                      + (float)pl[5 * SPL + row * SST + col];
            p += accm[rg] * x1v;
        }
        #pragma unroll
        for (int off = 32; off; off >>= 1) p += __shfl_xor(p, off, 64);
        if (lane == 0) rbuf[qw] = p;
    }
    __syncthreads();
    if (tid == 0) out[0] = -sqrtf(rbuf[0] + rbuf[1] + rbuf[2] + rbuf[3]);
}

extern "C" void kernel_launch(void* const* d_in, const int* in_sizes, int n_in,
                              void* d_out, int out_size, void* d_ws, size_t ws_size,
                              hipStream_t stream) {
    const float* H1 = (const float*)d_in[0];
    const float* H2 = (const float*)d_in[1];
    float* sig = (float*)d_ws;                      // 12288 floats = 48 KB
    float* part = (float*)((char*)d_ws + 49152);    // 1024 * 10240 floats = 40 MB
    const size_t need = 49152 + (size_t)GRID1 * 10240 * 4;

    if (ws_size >= need) {
        // No memset needed: reduce_kernel overwrites every sig slot solve reads.
        gram_kernel<true><<<GRID1, 256, 0, stream>>>(H1, H2, sig, part);
        reduce_kernel<<<160, 1024, 0, stream>>>(part, sig);
    } else {
        hipMemsetAsync(d_ws, 0, 49152, stream);
        gram_kernel<false><<<GRID1, 256, 0, stream>>>(H1, H2, sig, nullptr);
    }
    solve_kernel<<<1, 512, 0, stream>>>(sig, (float*)d_out);
}